// Round 1
// baseline (166.467 us; speedup 1.0000x reference)
//
#include <hip/hip_runtime.h>
#include <math.h>

#define DD 768          // hidden dim (in_sizes[0]/in_sizes[1] == 768)
#define S_LEN 512       // sequence length (reference setup)
#define NF4 3           // float4 chunks per lane: 768 / (64 lanes * 4)

__global__ __launch_bounds__(256) void zero_acc(float* acc, int n) {
    int i = blockIdx.x * 256 + threadIdx.x;
    if (i < n) acc[i] = 0.f;
}

// One wave per token. Lane `l` owns d-indices { k*256 + l*4 + j : k<3, j<4 },
// identical for every token the wave processes -> per-lane register accumulators.
__global__ __launch_bounds__(256) void main_pass(const float* __restrict__ logits,
                                                 const int* __restrict__ labels,
                                                 const int* __restrict__ eid_p,
                                                 int ntok,
                                                 float* __restrict__ acc) {
    const int eid  = *eid_p;
    const int lane = threadIdx.x & 63;
    const int wid  = threadIdx.x >> 6;
    const int gw   = blockIdx.x * 4 + wid;   // global wave id
    const int nw   = gridDim.x * 4;          // total waves

    float u_acc[12], p_acc[12];
#pragma unroll
    for (int j = 0; j < 12; ++j) { u_acc[j] = 0.f; p_acc[j] = 0.f; }
    float tokcnt = 0.f;

    for (int t = gw; t < ntok; t += nw) {
        const float4* src = (const float4*)(logits + (size_t)t * DD);
        float4 f[NF4];
#pragma unroll
        for (int k = 0; k < NF4; ++k) f[k] = src[k * 64 + lane];

        // per-token squared norm, wave-reduced
        float ss = 0.f;
#pragma unroll
        for (int k = 0; k < NF4; ++k)
            ss += f[k].x * f[k].x + f[k].y * f[k].y + f[k].z * f[k].z + f[k].w * f[k].w;
#pragma unroll
        for (int o = 32; o > 0; o >>= 1) ss += __shfl_xor(ss, o, 64);

        const int lbl = labels[t];
        const float inv = (ss > 0.f) ? rsqrtf(ss) : 0.f;
        const float wu  = (lbl != 0) ? inv : 0.f;                          // unit-vector weight
        const float wp  = (lbl == eid && (t & (S_LEN - 1)) != 0) ? 1.f : 0.f; // proto weight
        tokcnt += (lbl != 0) ? 1.f : 0.f;

#pragma unroll
        for (int k = 0; k < NF4; ++k) {
            u_acc[4 * k + 0] += f[k].x * wu;  p_acc[4 * k + 0] += f[k].x * wp;
            u_acc[4 * k + 1] += f[k].y * wu;  p_acc[4 * k + 1] += f[k].y * wp;
            u_acc[4 * k + 2] += f[k].z * wu;  p_acc[4 * k + 2] += f[k].z * wp;
            u_acc[4 * k + 3] += f[k].w * wu;  p_acc[4 * k + 3] += f[k].w * wp;
        }
    }

    // ---- block combine in LDS (4 waves take turns; within a wave, lanes
    // write disjoint d-indices, so plain add is race-free) ----
    __shared__ float sh[2 * DD + 1];
    for (int i = threadIdx.x; i < 2 * DD + 1; i += 256) sh[i] = 0.f;
    __syncthreads();
    for (int w = 0; w < 4; ++w) {
        if (wid == w) {
#pragma unroll
            for (int k = 0; k < NF4; ++k) {
                const int d = k * 256 + lane * 4;
                sh[d + 0]      += u_acc[4 * k + 0];
                sh[d + 1]      += u_acc[4 * k + 1];
                sh[d + 2]      += u_acc[4 * k + 2];
                sh[d + 3]      += u_acc[4 * k + 3];
                sh[DD + d + 0] += p_acc[4 * k + 0];
                sh[DD + d + 1] += p_acc[4 * k + 1];
                sh[DD + d + 2] += p_acc[4 * k + 2];
                sh[DD + d + 3] += p_acc[4 * k + 3];
            }
            if (lane == 0) sh[2 * DD] += tokcnt;
        }
        __syncthreads();
    }

    // ---- one atomic pass per block into the global accumulator ----
    for (int i = threadIdx.x; i < 2 * DD + 1; i += 256) atomicAdd(&acc[i], sh[i]);
}

// acc layout: u[0..767], p_sum[768..1535], num_tok at [1536]
__global__ __launch_bounds__(256) void finalize(const float* __restrict__ acc,
                                                float* __restrict__ out) {
    const int tid = threadIdx.x;
    double dup = 0.0, dpp = 0.0;
    for (int i = tid; i < DD; i += 256) {
        const double u = (double)acc[i];
        const double p = (double)acc[DD + i];
        dup += u * p;
        dpp += p * p;
    }
#pragma unroll
    for (int o = 32; o > 0; o >>= 1) {
        dup += __shfl_down(dup, o, 64);
        dpp += __shfl_down(dpp, o, 64);
    }
    __shared__ double s_up[4], s_pp[4];
    const int lane = tid & 63, wid = tid >> 6;
    if (lane == 0) { s_up[wid] = dup; s_pp[wid] = dpp; }
    __syncthreads();
    if (tid == 0) {
        double up = 0.0, pp = 0.0;
        for (int w = 0; w < 4; ++w) { up += s_up[w]; pp += s_pp[w]; }
        const float cnt = acc[2 * DD];
        float res = 0.f;
        if (pp > 0.0) res = (float)(up / (sqrt(pp) * (double)fmaxf(cnt, 1.f)));
        out[0] = res;
    }
}

extern "C" void kernel_launch(void* const* d_in, const int* in_sizes, int n_in,
                              void* d_out, int out_size, void* d_ws, size_t ws_size,
                              hipStream_t stream) {
    const float* logits = (const float*)d_in[0];
    const int*   labels = (const int*)d_in[1];
    const int*   eid    = (const int*)d_in[2];
    const int ntok = in_sizes[1];          // B*S = 32768
    float* acc = (float*)d_ws;             // needs (2*768+1)*4 = 6148 B

    zero_acc<<<7, 256, 0, stream>>>(acc, 2 * DD + 1);
    main_pass<<<1024, 256, 0, stream>>>(logits, labels, eid, ntok, acc);
    finalize<<<1, 256, 0, stream>>>(acc, (float*)d_out);
}

// Round 2
// 162.160 us; speedup vs baseline: 1.0266x; 1.0266x over previous
//
#include <hip/hip_runtime.h>
#include <math.h>

#define DD 768            // hidden dim
#define S_LEN 512         // sequence length
#define NF4 3             // float4 chunks per lane: 768 / (64*4)
#define NACC (2 * DD + 1) // u[768], p[768], num_tok  = 1537
#define PW 1544           // partial row stride (floats), 8-aligned
#define GMAIN 1024        // main-pass grid
#define BCHUNK 64         // partial rows reduced per stage-2 block

__global__ __launch_bounds__(256) void zero_acc(float* acc, int n) {
    int i = blockIdx.x * 256 + threadIdx.x;
    if (i < n) acc[i] = 0.f;
}

// One wave per token-stream. Lane l owns d-indices {k*256 + l*4 + j}.
// Epilogue: block-combine in LDS, then PLAIN coalesced store of the block's
// partial row (no global atomics -- R1 showed 1.57M same-line atomics cost
// ~140us of serialization at the L2 point of coherence).
__global__ __launch_bounds__(256) void main_pass(const float* __restrict__ logits,
                                                 const int* __restrict__ labels,
                                                 const int* __restrict__ eid_p,
                                                 int ntok,
                                                 float* __restrict__ partial) {
    const int eid  = *eid_p;
    const int lane = threadIdx.x & 63;
    const int wid  = threadIdx.x >> 6;
    const int gw   = blockIdx.x * 4 + wid;   // global wave id
    const int nw   = GMAIN * 4;              // total waves

    float u_acc[12], p_acc[12];
#pragma unroll
    for (int j = 0; j < 12; ++j) { u_acc[j] = 0.f; p_acc[j] = 0.f; }
    float tokcnt = 0.f;

    // process 2 independent tokens per iteration so the per-token serialized
    // shuffle-reduce chains overlap
    for (int t = gw; t < ntok; t += 2 * nw) {
        const int t2 = t + nw;
        const bool has2 = (t2 < ntok);

        const float4* src0 = (const float4*)(logits + (size_t)t * DD);
        const float4* src1 = (const float4*)(logits + (size_t)(has2 ? t2 : t) * DD);
        float4 f0[NF4], f1[NF4];
#pragma unroll
        for (int k = 0; k < NF4; ++k) f0[k] = src0[k * 64 + lane];
#pragma unroll
        for (int k = 0; k < NF4; ++k) f1[k] = src1[k * 64 + lane];

        float ss0 = 0.f, ss1 = 0.f;
#pragma unroll
        for (int k = 0; k < NF4; ++k) {
            ss0 += f0[k].x * f0[k].x + f0[k].y * f0[k].y + f0[k].z * f0[k].z + f0[k].w * f0[k].w;
            ss1 += f1[k].x * f1[k].x + f1[k].y * f1[k].y + f1[k].z * f1[k].z + f1[k].w * f1[k].w;
        }
#pragma unroll
        for (int o = 32; o > 0; o >>= 1) {
            ss0 += __shfl_xor(ss0, o, 64);
            ss1 += __shfl_xor(ss1, o, 64);
        }

        const int lbl0 = labels[t];
        const int lbl1 = has2 ? labels[t2] : 0;

        const float inv0 = (ss0 > 0.f) ? rsqrtf(ss0) : 0.f;
        const float inv1 = (ss1 > 0.f) ? rsqrtf(ss1) : 0.f;
        const float wu0  = (lbl0 != 0) ? inv0 : 0.f;
        const float wu1  = (has2 && lbl1 != 0) ? inv1 : 0.f;
        const float wp0  = (lbl0 == eid && (t & (S_LEN - 1)) != 0) ? 1.f : 0.f;
        const float wp1  = (has2 && lbl1 == eid && (t2 & (S_LEN - 1)) != 0) ? 1.f : 0.f;
        tokcnt += ((lbl0 != 0) ? 1.f : 0.f) + ((has2 && lbl1 != 0) ? 1.f : 0.f);

#pragma unroll
        for (int k = 0; k < NF4; ++k) {
            u_acc[4 * k + 0] += f0[k].x * wu0 + f1[k].x * wu1;
            u_acc[4 * k + 1] += f0[k].y * wu0 + f1[k].y * wu1;
            u_acc[4 * k + 2] += f0[k].z * wu0 + f1[k].z * wu1;
            u_acc[4 * k + 3] += f0[k].w * wu0 + f1[k].w * wu1;
            p_acc[4 * k + 0] += f0[k].x * wp0 + f1[k].x * wp1;
            p_acc[4 * k + 1] += f0[k].y * wp0 + f1[k].y * wp1;
            p_acc[4 * k + 2] += f0[k].z * wp0 + f1[k].z * wp1;
            p_acc[4 * k + 3] += f0[k].w * wp0 + f1[k].w * wp1;
        }
    }

    // ---- block combine in LDS (4 waves take turns; lanes write disjoint d) ----
    __shared__ float sh[NACC];
    for (int i = threadIdx.x; i < NACC; i += 256) sh[i] = 0.f;
    __syncthreads();
    for (int w = 0; w < 4; ++w) {
        if (wid == w) {
#pragma unroll
            for (int k = 0; k < NF4; ++k) {
                const int d = k * 256 + lane * 4;
                sh[d + 0]      += u_acc[4 * k + 0];
                sh[d + 1]      += u_acc[4 * k + 1];
                sh[d + 2]      += u_acc[4 * k + 2];
                sh[d + 3]      += u_acc[4 * k + 3];
                sh[DD + d + 0] += p_acc[4 * k + 0];
                sh[DD + d + 1] += p_acc[4 * k + 1];
                sh[DD + d + 2] += p_acc[4 * k + 2];
                sh[DD + d + 3] += p_acc[4 * k + 3];
            }
            if (lane == 0) sh[2 * DD] += tokcnt;
        }
        __syncthreads();
    }

    // ---- plain coalesced store of this block's partial row ----
    float* row = partial + (size_t)blockIdx.x * PW;
    for (int i = threadIdx.x; i < NACC; i += 256) row[i] = sh[i];
}

// grid (7, GMAIN/BCHUNK): x = dim chunk (256 dims), y = partial-row chunk.
// Only 7*16*256 ~= 28K atomics, 16-way contention per address -> negligible.
__global__ __launch_bounds__(256) void reduce_partials(const float* __restrict__ partial,
                                                       float* __restrict__ acc) {
    const int i = blockIdx.x * 256 + threadIdx.x;
    if (i >= NACC) return;
    const int b0 = blockIdx.y * BCHUNK;
    float s0 = 0.f, s1 = 0.f, s2 = 0.f, s3 = 0.f;
#pragma unroll 4
    for (int j = 0; j < BCHUNK; j += 4) {
        s0 += partial[(size_t)(b0 + j + 0) * PW + i];
        s1 += partial[(size_t)(b0 + j + 1) * PW + i];
        s2 += partial[(size_t)(b0 + j + 2) * PW + i];
        s3 += partial[(size_t)(b0 + j + 3) * PW + i];
    }
    atomicAdd(&acc[i], (s0 + s1) + (s2 + s3));
}

// acc layout: u[0..767], p_sum[768..1535], num_tok at [1536]
__global__ __launch_bounds__(256) void finalize(const float* __restrict__ acc,
                                                float* __restrict__ out) {
    const int tid = threadIdx.x;
    double dup = 0.0, dpp = 0.0;
    for (int i = tid; i < DD; i += 256) {
        const double u = (double)acc[i];
        const double p = (double)acc[DD + i];
        dup += u * p;
        dpp += p * p;
    }
#pragma unroll
    for (int o = 32; o > 0; o >>= 1) {
        dup += __shfl_down(dup, o, 64);
        dpp += __shfl_down(dpp, o, 64);
    }
    __shared__ double s_up[4], s_pp[4];
    const int lane = tid & 63, wid = tid >> 6;
    if (lane == 0) { s_up[wid] = dup; s_pp[wid] = dpp; }
    __syncthreads();
    if (tid == 0) {
        double up = 0.0, pp = 0.0;
        for (int w = 0; w < 4; ++w) { up += s_up[w]; pp += s_pp[w]; }
        const float cnt = acc[2 * DD];
        float res = 0.f;
        if (pp > 0.0) res = (float)(up / (sqrt(pp) * (double)fmaxf(cnt, 1.f)));
        out[0] = res;
    }
}

extern "C" void kernel_launch(void* const* d_in, const int* in_sizes, int n_in,
                              void* d_out, int out_size, void* d_ws, size_t ws_size,
                              hipStream_t stream) {
    const float* logits = (const float*)d_in[0];
    const int*   labels = (const int*)d_in[1];
    const int*   eid    = (const int*)d_in[2];
    const int ntok = in_sizes[1];          // B*S = 32768

    float* acc     = (float*)d_ws;                 // NACC floats
    float* partial = (float*)d_ws + 2048;          // GMAIN rows of PW floats (~6.3 MB)

    zero_acc<<<7, 256, 0, stream>>>(acc, NACC);
    main_pass<<<GMAIN, 256, 0, stream>>>(logits, labels, eid, ntok, partial);
    reduce_partials<<<dim3(7, GMAIN / BCHUNK), 256, 0, stream>>>(partial, acc);
    finalize<<<1, 256, 0, stream>>>(acc, (float*)d_out);
}

// Round 3
// 158.113 us; speedup vs baseline: 1.0528x; 1.0256x over previous
//
#include <hip/hip_runtime.h>
#include <math.h>

#define DD 768            // hidden dim
#define S_LEN 512         // sequence length
#define NF4 3             // float4 chunks per lane: 768 / (64*4)
#define NACC (2 * DD + 1) // u[768], p[768], num_tok = 1537
#define PW 1544           // partial row stride (floats), 8-aligned
#define GMAIN 1024        // main-pass grid
#define NYB 16            // stage-2 y-blocks
#define BCHUNK (GMAIN / NYB) // partial rows reduced per stage-2 block (64)

// One wave per token-stream. Lane l owns d-indices {k*256 + l*4 + j}.
// Epilogue: block-combine in LDS, plain coalesced store of the block's
// partial row. (R1 lesson: global same-line atomics at 1.57M ops cost ~4us;
// R2 lesson: total dur is dominated by ~135us of harness d_ws re-poison +
// d_in restore fills -- our controllable window is only ~25us.)
__global__ __launch_bounds__(256) void main_pass(const float* __restrict__ logits,
                                                 const int* __restrict__ labels,
                                                 const int* __restrict__ eid_p,
                                                 int ntok,
                                                 float* __restrict__ partial) {
    const int eid  = *eid_p;
    const int lane = threadIdx.x & 63;
    const int wid  = threadIdx.x >> 6;
    const int gw   = blockIdx.x * 4 + wid;   // global wave id
    const int nw   = GMAIN * 4;              // total waves

    float u_acc[12], p_acc[12];
#pragma unroll
    for (int j = 0; j < 12; ++j) { u_acc[j] = 0.f; p_acc[j] = 0.f; }
    float tokcnt = 0.f;

    // two independent tokens per iteration: overlap the serialized
    // shuffle-reduce chains and double outstanding loads
    for (int t = gw; t < ntok; t += 2 * nw) {
        const int t2 = t + nw;
        const bool has2 = (t2 < ntok);

        const float4* src0 = (const float4*)(logits + (size_t)t * DD);
        const float4* src1 = (const float4*)(logits + (size_t)(has2 ? t2 : t) * DD);
        float4 f0[NF4], f1[NF4];
#pragma unroll
        for (int k = 0; k < NF4; ++k) f0[k] = src0[k * 64 + lane];
#pragma unroll
        for (int k = 0; k < NF4; ++k) f1[k] = src1[k * 64 + lane];

        float ss0 = 0.f, ss1 = 0.f;
#pragma unroll
        for (int k = 0; k < NF4; ++k) {
            ss0 += f0[k].x * f0[k].x + f0[k].y * f0[k].y + f0[k].z * f0[k].z + f0[k].w * f0[k].w;
            ss1 += f1[k].x * f1[k].x + f1[k].y * f1[k].y + f1[k].z * f1[k].z + f1[k].w * f1[k].w;
        }
#pragma unroll
        for (int o = 32; o > 0; o >>= 1) {
            ss0 += __shfl_xor(ss0, o, 64);
            ss1 += __shfl_xor(ss1, o, 64);
        }

        const int lbl0 = labels[t];
        const int lbl1 = has2 ? labels[t2] : 0;

        const float inv0 = (ss0 > 0.f) ? rsqrtf(ss0) : 0.f;
        const float inv1 = (ss1 > 0.f) ? rsqrtf(ss1) : 0.f;
        const float wu0  = (lbl0 != 0) ? inv0 : 0.f;
        const float wu1  = (has2 && lbl1 != 0) ? inv1 : 0.f;
        const float wp0  = (lbl0 == eid && (t & (S_LEN - 1)) != 0) ? 1.f : 0.f;
        const float wp1  = (has2 && lbl1 == eid && (t2 & (S_LEN - 1)) != 0) ? 1.f : 0.f;
        tokcnt += ((lbl0 != 0) ? 1.f : 0.f) + ((has2 && lbl1 != 0) ? 1.f : 0.f);

#pragma unroll
        for (int k = 0; k < NF4; ++k) {
            u_acc[4 * k + 0] += f0[k].x * wu0 + f1[k].x * wu1;
            u_acc[4 * k + 1] += f0[k].y * wu0 + f1[k].y * wu1;
            u_acc[4 * k + 2] += f0[k].z * wu0 + f1[k].z * wu1;
            u_acc[4 * k + 3] += f0[k].w * wu0 + f1[k].w * wu1;
            p_acc[4 * k + 0] += f0[k].x * wp0 + f1[k].x * wp1;
            p_acc[4 * k + 1] += f0[k].y * wp0 + f1[k].y * wp1;
            p_acc[4 * k + 2] += f0[k].z * wp0 + f1[k].z * wp1;
            p_acc[4 * k + 3] += f0[k].w * wp0 + f1[k].w * wp1;
        }
    }

    // ---- block combine in LDS (4 waves take turns; lanes write disjoint d) ----
    __shared__ float sh[NACC];
    for (int i = threadIdx.x; i < NACC; i += 256) sh[i] = 0.f;
    __syncthreads();
    for (int w = 0; w < 4; ++w) {
        if (wid == w) {
#pragma unroll
            for (int k = 0; k < NF4; ++k) {
                const int d = k * 256 + lane * 4;
                sh[d + 0]      += u_acc[4 * k + 0];
                sh[d + 1]      += u_acc[4 * k + 1];
                sh[d + 2]      += u_acc[4 * k + 2];
                sh[d + 3]      += u_acc[4 * k + 3];
                sh[DD + d + 0] += p_acc[4 * k + 0];
                sh[DD + d + 1] += p_acc[4 * k + 1];
                sh[DD + d + 2] += p_acc[4 * k + 2];
                sh[DD + d + 3] += p_acc[4 * k + 3];
            }
            if (lane == 0) sh[2 * DD] += tokcnt;
        }
        __syncthreads();
    }

    // ---- plain coalesced store of this block's partial row ----
    float* row = partial + (size_t)blockIdx.x * PW;
    for (int i = threadIdx.x; i < NACC; i += 256) row[i] = sh[i];
}

// grid (7, NYB): block (x,y) sums BCHUNK partial rows for its 256-dim chunk
// and writes acc2[y] -- disjoint outputs, no atomics, no zero kernel needed.
__global__ __launch_bounds__(256) void reduce_partials(const float* __restrict__ partial,
                                                       float* __restrict__ acc2) {
    const int i = blockIdx.x * 256 + threadIdx.x;
    if (i >= NACC) return;
    const int b0 = blockIdx.y * BCHUNK;
    float s0 = 0.f, s1 = 0.f, s2 = 0.f, s3 = 0.f;
#pragma unroll 4
    for (int j = 0; j < BCHUNK; j += 4) {
        s0 += partial[(size_t)(b0 + j + 0) * PW + i];
        s1 += partial[(size_t)(b0 + j + 1) * PW + i];
        s2 += partial[(size_t)(b0 + j + 2) * PW + i];
        s3 += partial[(size_t)(b0 + j + 3) * PW + i];
    }
    acc2[(size_t)blockIdx.y * PW + i] = (s0 + s1) + (s2 + s3);
}

// Single block: fold NYB rows (98 KB) and compute the final scalar.
__global__ __launch_bounds__(256) void finalize(const float* __restrict__ acc2,
                                                float* __restrict__ out) {
    const int tid = threadIdx.x;
    double dup = 0.0, dpp = 0.0;
    for (int i = tid; i < DD; i += 256) {
        float u = 0.f, p = 0.f;
#pragma unroll
        for (int y = 0; y < NYB; ++y) {
            u += acc2[(size_t)y * PW + i];
            p += acc2[(size_t)y * PW + DD + i];
        }
        dup += (double)u * (double)p;
        dpp += (double)p * (double)p;
    }
#pragma unroll
    for (int o = 32; o > 0; o >>= 1) {
        dup += __shfl_down(dup, o, 64);
        dpp += __shfl_down(dpp, o, 64);
    }
    __shared__ double s_up[4], s_pp[4];
    const int lane = tid & 63, wid = tid >> 6;
    if (lane == 0) { s_up[wid] = dup; s_pp[wid] = dpp; }
    __syncthreads();
    if (tid == 0) {
        double up = 0.0, pp = 0.0;
        for (int w = 0; w < 4; ++w) { up += s_up[w]; pp += s_pp[w]; }
        float cnt = 0.f;
#pragma unroll
        for (int y = 0; y < NYB; ++y) cnt += acc2[(size_t)y * PW + 2 * DD];
        float res = 0.f;
        if (pp > 0.0) res = (float)(up / (sqrt(pp) * (double)fmaxf(cnt, 1.f)));
        out[0] = res;
    }
}

extern "C" void kernel_launch(void* const* d_in, const int* in_sizes, int n_in,
                              void* d_out, int out_size, void* d_ws, size_t ws_size,
                              hipStream_t stream) {
    const float* logits = (const float*)d_in[0];
    const int*   labels = (const int*)d_in[1];
    const int*   eid    = (const int*)d_in[2];
    const int ntok = in_sizes[1];          // B*S = 32768

    float* partial = (float*)d_ws;                          // GMAIN rows x PW floats (~6.3 MB)
    float* acc2    = (float*)d_ws + (size_t)GMAIN * PW;     // NYB rows x PW floats

    main_pass<<<GMAIN, 256, 0, stream>>>(logits, labels, eid, ntok, partial);
    reduce_partials<<<dim3(7, NYB), 256, 0, stream>>>(partial, acc2);
    finalize<<<1, 256, 0, stream>>>(acc2, (float*)d_out);
}

// Round 4
// 155.219 us; speedup vs baseline: 1.0725x; 1.0186x over previous
//
#include <hip/hip_runtime.h>
#include <math.h>

#define DD 768            // hidden dim
#define S_LEN 512         // sequence length
#define NF4 3             // float4 chunks per lane: 768 / (64*4)
#define NACC (2 * DD + 1) // u[768], p[768], num_tok = 1537
#define PW 1544           // partial row stride (floats), 8-aligned
#define GMAIN 512         // main-pass grid (2 blocks/CU, 8 waves/CU)
#define NWAVES (GMAIN * 4)
#define NYB 16            // stage-2 y-blocks
#define BCHUNK (GMAIN / NYB) // partial rows per stage-2 block (32)

// One wave per token-stream; lane l owns d-indices {k*256 + l*4 + j}.
// R2/R3 lessons: total dur is dominated by ~135us of harness d_ws re-poison
// + d_in restore; our controllable slice is ~23us. This round: skip
// label==0 tokens entirely (wave-uniform, ~10% of reads), halve the
// partial-row traffic (GMAIN 512), and make proto-accumulate conditional
// (wave-uniform branch, ~90% of tokens skip those 12 FMAs).
__global__ __launch_bounds__(256) void main_pass(const float* __restrict__ logits,
                                                 const int* __restrict__ labels,
                                                 const int* __restrict__ eid_p,
                                                 int ntok,
                                                 float* __restrict__ partial) {
    const int eid  = *eid_p;
    const int lane = threadIdx.x & 63;
    const int wid  = threadIdx.x >> 6;
    const int gw   = blockIdx.x * 4 + wid;   // global wave id

    // prefetch this wave's labels: lane j holds labels[gw + j*NWAVES], j<16
    int lblv = 0;
    if (lane < 16) {
        const int tj = gw + lane * NWAVES;
        if (tj < ntok) lblv = labels[tj];
    }

    float u_acc[12], p_acc[12];
#pragma unroll
    for (int j = 0; j < 12; ++j) { u_acc[j] = 0.f; p_acc[j] = 0.f; }
    float tokcnt = 0.f;

    for (int j = 0;; ++j) {
        const int t = gw + j * NWAVES;
        if (t >= ntok) break;
        const int lbl = (j < 16) ? __shfl(lblv, j, 64) : labels[t];

        // token contributes iff it has a nonzero label (cos-sim term) or is a
        // proto token (lbl==eid; only possible here with lbl==0 if eid==0)
        if (lbl == 0 && eid != 0) continue;   // wave-uniform skip, ~10% of tokens

        const float4* src = (const float4*)(logits + (size_t)t * DD);
        float4 f[NF4];
#pragma unroll
        for (int k = 0; k < NF4; ++k) f[k] = src[k * 64 + lane];

        float ss = 0.f;
#pragma unroll
        for (int k = 0; k < NF4; ++k)
            ss += f[k].x * f[k].x + f[k].y * f[k].y + f[k].z * f[k].z + f[k].w * f[k].w;
#pragma unroll
        for (int o = 32; o > 0; o >>= 1) ss += __shfl_xor(ss, o, 64);

        if (lbl != 0) {                        // wave-uniform
            const float inv = (ss > 0.f) ? rsqrtf(ss) : 0.f;
            tokcnt += 1.f;
#pragma unroll
            for (int k = 0; k < NF4; ++k) {
                u_acc[4 * k + 0] += f[k].x * inv;
                u_acc[4 * k + 1] += f[k].y * inv;
                u_acc[4 * k + 2] += f[k].z * inv;
                u_acc[4 * k + 3] += f[k].w * inv;
            }
        }
        if (lbl == eid && (t & (S_LEN - 1)) != 0) {  // wave-uniform, ~10%
#pragma unroll
            for (int k = 0; k < NF4; ++k) {
                p_acc[4 * k + 0] += f[k].x;
                p_acc[4 * k + 1] += f[k].y;
                p_acc[4 * k + 2] += f[k].z;
                p_acc[4 * k + 3] += f[k].w;
            }
        }
    }

    // ---- block combine in LDS (4 waves take turns; lanes write disjoint d) ----
    __shared__ float sh[NACC];
    for (int i = threadIdx.x; i < NACC; i += 256) sh[i] = 0.f;
    __syncthreads();
    for (int w = 0; w < 4; ++w) {
        if (wid == w) {
#pragma unroll
            for (int k = 0; k < NF4; ++k) {
                const int d = k * 256 + lane * 4;
                sh[d + 0]      += u_acc[4 * k + 0];
                sh[d + 1]      += u_acc[4 * k + 1];
                sh[d + 2]      += u_acc[4 * k + 2];
                sh[d + 3]      += u_acc[4 * k + 3];
                sh[DD + d + 0] += p_acc[4 * k + 0];
                sh[DD + d + 1] += p_acc[4 * k + 1];
                sh[DD + d + 2] += p_acc[4 * k + 2];
                sh[DD + d + 3] += p_acc[4 * k + 3];
            }
            if (lane == 0) sh[2 * DD] += tokcnt;
        }
        __syncthreads();
    }

    // ---- plain coalesced store of this block's partial row ----
    float* row = partial + (size_t)blockIdx.x * PW;
    for (int i = threadIdx.x; i < NACC; i += 256) row[i] = sh[i];
}

// grid (7, NYB): block (x,y) sums BCHUNK partial rows for its 256-dim chunk,
// writes acc2[y] -- disjoint outputs, no atomics, no zero-init needed.
__global__ __launch_bounds__(256) void reduce_partials(const float* __restrict__ partial,
                                                       float* __restrict__ acc2) {
    const int i = blockIdx.x * 256 + threadIdx.x;
    if (i >= NACC) return;
    const int b0 = blockIdx.y * BCHUNK;
    float s0 = 0.f, s1 = 0.f, s2 = 0.f, s3 = 0.f;
#pragma unroll 4
    for (int j = 0; j < BCHUNK; j += 4) {
        s0 += partial[(size_t)(b0 + j + 0) * PW + i];
        s1 += partial[(size_t)(b0 + j + 1) * PW + i];
        s2 += partial[(size_t)(b0 + j + 2) * PW + i];
        s3 += partial[(size_t)(b0 + j + 3) * PW + i];
    }
    acc2[(size_t)blockIdx.y * PW + i] = (s0 + s1) + (s2 + s3);
}

// Single block: fold NYB rows (~98 KB, L2-warm) and compute the final scalar.
__global__ __launch_bounds__(256) void finalize(const float* __restrict__ acc2,
                                                float* __restrict__ out) {
    const int tid = threadIdx.x;
    double dup = 0.0, dpp = 0.0;
    for (int i = tid; i < DD; i += 256) {
        float u = 0.f, p = 0.f;
#pragma unroll
        for (int y = 0; y < NYB; ++y) {
            u += acc2[(size_t)y * PW + i];
            p += acc2[(size_t)y * PW + DD + i];
        }
        dup += (double)u * (double)p;
        dpp += (double)p * (double)p;
    }
#pragma unroll
    for (int o = 32; o > 0; o >>= 1) {
        dup += __shfl_down(dup, o, 64);
        dpp += __shfl_down(dpp, o, 64);
    }
    __shared__ double s_up[4], s_pp[4];
    const int lane = tid & 63, wid = tid >> 6;
    if (lane == 0) { s_up[wid] = dup; s_pp[wid] = dpp; }
    __syncthreads();
    if (tid == 0) {
        double up = 0.0, pp = 0.0;
        for (int w = 0; w < 4; ++w) { up += s_up[w]; pp += s_pp[w]; }
        float cnt = 0.f;
#pragma unroll
        for (int y = 0; y < NYB; ++y) cnt += acc2[(size_t)y * PW + 2 * DD];
        float res = 0.f;
        if (pp > 0.0) res = (float)(up / (sqrt(pp) * (double)fmaxf(cnt, 1.f)));
        out[0] = res;
    }
}

extern "C" void kernel_launch(void* const* d_in, const int* in_sizes, int n_in,
                              void* d_out, int out_size, void* d_ws, size_t ws_size,
                              hipStream_t stream) {
    const float* logits = (const float*)d_in[0];
    const int*   labels = (const int*)d_in[1];
    const int*   eid    = (const int*)d_in[2];
    const int ntok = in_sizes[1];          // B*S = 32768

    float* partial = (float*)d_ws;                          // GMAIN rows x PW floats (~3.2 MB)
    float* acc2    = (float*)d_ws + (size_t)GMAIN * PW;     // NYB rows x PW floats

    main_pass<<<GMAIN, 256, 0, stream>>>(logits, labels, eid, ntok, partial);
    reduce_partials<<<dim3(7, NYB), 256, 0, stream>>>(partial, acc2);
    finalize<<<1, 256, 0, stream>>>(acc2, (float*)d_out);
}